// Round 1
// baseline (8056.779 us; speedup 1.0000x reference)
//
#include <hip/hip_runtime.h>
#include <math.h>

#define D_MODEL 1024
#define D_INNER 2048
#define D_STATE 16
#define DT_RANK 64
#define D_CONV  4
#define N_LAYER 4
#define VOCAB   32000
#define EPS     1e-5f
#define BSZ     2
#define LSEQ    1024
#define NTOK    (BSZ*LSEQ)      // 2048 token rows

#define LOG2E   1.4426950408889634f

// ---------------------------------------------------------------- embedding
__global__ void embed_k(const int* __restrict__ tokens,
                        const float* __restrict__ emb,
                        float* __restrict__ x) {
    int row = blockIdx.x;                       // 0..2047
    int t = tokens[row];
    const float4* src = (const float4*)(emb + (size_t)t * D_MODEL);
    float4* dst = (float4*)(x + (size_t)row * D_MODEL);
    dst[threadIdx.x] = src[threadIdx.x];        // 256 thr * 4 = 1024
}

// ---------------------------------------------------------------- rmsnorm
__global__ __launch_bounds__(256) void rmsnorm_k(const float* __restrict__ x,
                                                 const float* __restrict__ w,
                                                 float* __restrict__ o) {
    int row = blockIdx.x;
    const float4* xr = (const float4*)(x + (size_t)row * D_MODEL);
    float4 v = xr[threadIdx.x];
    float ss = v.x*v.x + v.y*v.y + v.z*v.z + v.w*v.w;
    #pragma unroll
    for (int off = 32; off > 0; off >>= 1) ss += __shfl_down(ss, off, 64);
    __shared__ float sred[4];
    int wid = threadIdx.x >> 6, lane = threadIdx.x & 63;
    if (lane == 0) sred[wid] = ss;
    __syncthreads();
    float tot = sred[0] + sred[1] + sred[2] + sred[3];
    float scale = rsqrtf(tot * (1.0f / D_MODEL) + EPS);
    float4 wv = ((const float4*)w)[threadIdx.x];
    float4 ov;
    ov.x = v.x * scale * wv.x;
    ov.y = v.y * scale * wv.y;
    ov.z = v.z * scale * wv.z;
    ov.w = v.w * scale * wv.w;
    ((float4*)(o + (size_t)row * D_MODEL))[threadIdx.x] = ov;
}

// ---------------------------------------------------------------- fp32 GEMM
// C[M,N] = A[M,K(lda)] @ B[K,N]   (row-major)
// MODE 0: plain    MODE 1: +bias[col], softplus    MODE 2: +aux[row,col] (residual)
// 64x64 tile, 256 threads, 4x4 per-thread micro-tile, K-tile 16.
template<int MODE>
__global__ __launch_bounds__(256) void gemm_k(const float* __restrict__ A,
                                              const float* __restrict__ B,
                                              float* __restrict__ C,
                                              int M, int N, int K, int lda,
                                              const float* __restrict__ aux) {
    __shared__ float As[16][68];   // [k][m], row stride 68 floats = 17*16B (f4-aligned)
    __shared__ float Bs[16][68];   // [k][n]
    int tid = threadIdx.x;
    int tx = tid & 15, ty = tid >> 4;
    int rowBase = blockIdx.y * 64;
    int colBase = blockIdx.x * 64;
    float acc[4][4] = {};

    for (int k0 = 0; k0 < K; k0 += 16) {
        #pragma unroll
        for (int i = 0; i < 4; i++) {           // A tile: 64 rows x 16 k
            int lin = tid + i * 256;
            int r = lin >> 4, kk = lin & 15;
            As[kk][r] = A[(size_t)(rowBase + r) * lda + k0 + kk];
        }
        #pragma unroll
        for (int i = 0; i < 4; i++) {           // B tile: 16 k x 64 cols
            int lin = tid + i * 256;
            int kk = lin >> 6, c = lin & 63;
            int col = colBase + c;
            Bs[kk][c] = (col < N) ? B[(size_t)(k0 + kk) * N + col] : 0.f;
        }
        __syncthreads();
        #pragma unroll
        for (int kk = 0; kk < 16; kk++) {
            float4 a4 = *(const float4*)&As[kk][ty * 4];
            float4 b4 = *(const float4*)&Bs[kk][tx * 4];
            float av[4] = {a4.x, a4.y, a4.z, a4.w};
            float bv[4] = {b4.x, b4.y, b4.z, b4.w};
            #pragma unroll
            for (int i = 0; i < 4; i++)
                #pragma unroll
                for (int j = 0; j < 4; j++)
                    acc[i][j] = fmaf(av[i], bv[j], acc[i][j]);
        }
        __syncthreads();
    }

    int col = colBase + tx * 4;                 // N % 4 == 0 for all our calls
    if (col < N) {
        #pragma unroll
        for (int i = 0; i < 4; i++) {
            int row = rowBase + ty * 4 + i;
            float v0 = acc[i][0], v1 = acc[i][1], v2 = acc[i][2], v3 = acc[i][3];
            if (MODE == 1) {
                const float4 bb = *(const float4*)&aux[col];
                v0 += bb.x; v1 += bb.y; v2 += bb.z; v3 += bb.w;
                v0 = (v0 > 20.f) ? v0 : log1pf(__expf(v0));
                v1 = (v1 > 20.f) ? v1 : log1pf(__expf(v1));
                v2 = (v2 > 20.f) ? v2 : log1pf(__expf(v2));
                v3 = (v3 > 20.f) ? v3 : log1pf(__expf(v3));
            } else if (MODE == 2) {
                const float4 rr = *(const float4*)&aux[(size_t)row * N + col];
                v0 += rr.x; v1 += rr.y; v2 += rr.z; v3 += rr.w;
            }
            float4 ov; ov.x = v0; ov.y = v1; ov.z = v2; ov.w = v3;
            *(float4*)&C[(size_t)row * N + col] = ov;
        }
    }
}

// ---------------------------------------------------------------- conv1d + silu
// u[t,d] = silu( cb[d] + sum_k cw[d,k] * xz[t-3+k, d] )   (u-half of xz, causal in l)
__global__ __launch_bounds__(256) void conv_silu_k(const float* __restrict__ xz,
                                                   const float* __restrict__ cw,
                                                   const float* __restrict__ cb,
                                                   float* __restrict__ u) {
    int d = blockIdx.x * 256 + threadIdx.x;     // 0..2047
    int t = blockIdx.y;                          // b*L + l
    int l = t & (LSEQ - 1);
    float acc = cb[d];
    #pragma unroll
    for (int k = 0; k < D_CONV; k++) {
        int ll = l - (D_CONV - 1) + k;
        if (ll >= 0)
            acc = fmaf(cw[d * D_CONV + k], xz[(size_t)(t - (D_CONV - 1) + k) * (2 * D_INNER) + d], acc);
    }
    float s = acc / (1.f + __expf(-acc));        // silu
    u[(size_t)t * D_INNER + d] = s;
}

// ---------------------------------------------------------------- selective scan
// thread owns (b, d); h[16] in registers; B/C staged in LDS per 32-l chunk.
__global__ __launch_bounds__(256) void scan_k(const float* __restrict__ u,
                                              const float* __restrict__ dt,
                                              const float* __restrict__ dbl,
                                              const float* __restrict__ A_log,
                                              const float* __restrict__ Dp,
                                              float* __restrict__ y) {
    int b = blockIdx.x >> 3;                     // 8 blocks per batch
    int d = (blockIdx.x & 7) * 256 + threadIdx.x;
    float A2[D_STATE];
    #pragma unroll
    for (int n = 0; n < D_STATE; n++)
        A2[n] = -__expf(A_log[(size_t)d * D_STATE + n]) * LOG2E;   // A * log2(e)
    float Dd = Dp[d];
    float h[D_STATE];
    #pragma unroll
    for (int n = 0; n < D_STATE; n++) h[n] = 0.f;

    __shared__ float bc[32][32];                 // [l-chunk][B(16)|C(16)]
    for (int c0 = 0; c0 < LSEQ; c0 += 32) {
        __syncthreads();
        #pragma unroll
        for (int i = 0; i < 4; i++) {
            int lin = threadIdx.x + i * 256;
            int li = lin >> 5, j = lin & 31;
            bc[li][j] = dbl[(size_t)(b * LSEQ + c0 + li) * 96 + 64 + j];
        }
        __syncthreads();
        for (int li = 0; li < 32; li++) {
            int t = b * LSEQ + c0 + li;
            float dtv = dt[(size_t)t * D_INNER + d];
            float uv  = u[(size_t)t * D_INNER + d];
            float dbu = dtv * uv;
            float yv = 0.f;
            #pragma unroll
            for (int n = 0; n < D_STATE; n++) {
                float dA = exp2f(dtv * A2[n]);
                h[n] = fmaf(dA, h[n], dbu * bc[li][n]);
                yv = fmaf(h[n], bc[li][16 + n], yv);
            }
            y[(size_t)t * D_INNER + d] = yv + uv * Dd;
        }
    }
}

// ---------------------------------------------------------------- gate: y *= silu(z)
__global__ __launch_bounds__(256) void gate_k(const float* __restrict__ xz,
                                              float* __restrict__ y) {
    size_t i = (size_t)blockIdx.x * 256 + threadIdx.x;   // over NTOK*D_INNER
    size_t t = i >> 11;                                   // / D_INNER
    int d = (int)(i & (D_INNER - 1));
    float z = xz[t * (2 * D_INNER) + D_INNER + d];
    y[i] *= z / (1.f + __expf(-z));
}

// ---------------------------------------------------------------- launch
extern "C" void kernel_launch(void* const* d_in, const int* in_sizes, int n_in,
                              void* d_out, int out_size, void* d_ws, size_t ws_size,
                              hipStream_t stream) {
    const int*   tokens   = (const int*)  d_in[0];
    const float* emb      = (const float*)d_in[1];
    const float* norm_w   = (const float*)d_in[2];
    const float* in_proj  = (const float*)d_in[3];
    const float* conv_w   = (const float*)d_in[4];
    const float* conv_b   = (const float*)d_in[5];
    const float* x_proj   = (const float*)d_in[6];
    const float* dt_w     = (const float*)d_in[7];
    const float* dt_b     = (const float*)d_in[8];
    const float* A_log    = (const float*)d_in[9];
    const float* Dp       = (const float*)d_in[10];
    const float* out_proj = (const float*)d_in[11];
    const float* fin_w    = (const float*)d_in[12];
    const float* head_w   = (const float*)d_in[13];
    float* out = (float*)d_out;

    // small persistent scratch in d_ws (~17.6 MB)
    float* ws  = (float*)d_ws;
    float* x   = ws;                       // 2,097,152
    float* xn  = ws + 2097152;             // 2,097,152
    float* dbl = ws + 4194304;             //   196,608

    // big transient scratch inside d_out (overwritten by head GEMM at the end)
    float* xz = out;                       // 8,388,608  [2048 x 4096]
    float* u  = out + 8388608;             // 4,194,304  [2048 x 2048]
    float* dt = out + 12582912;            // 4,194,304
    float* y  = out + 16777216;            // 4,194,304

    embed_k<<<NTOK, 256, 0, stream>>>(tokens, emb, x);

    for (int i = 0; i < N_LAYER; i++) {
        rmsnorm_k<<<NTOK, 256, 0, stream>>>(x, norm_w + (size_t)i * D_MODEL, xn);
        gemm_k<0><<<dim3(64, 32), 256, 0, stream>>>(
            xn, in_proj + (size_t)i * D_MODEL * 2 * D_INNER, xz,
            NTOK, 2 * D_INNER, D_MODEL, D_MODEL, nullptr);
        conv_silu_k<<<dim3(8, NTOK), 256, 0, stream>>>(
            xz, conv_w + (size_t)i * D_INNER * D_CONV, conv_b + (size_t)i * D_INNER, u);
        gemm_k<0><<<dim3(2, 32), 256, 0, stream>>>(
            u, x_proj + (size_t)i * D_INNER * 96, dbl,
            NTOK, 96, D_INNER, D_INNER, nullptr);
        gemm_k<1><<<dim3(32, 32), 256, 0, stream>>>(
            dbl, dt_w + (size_t)i * DT_RANK * D_INNER, dt,
            NTOK, D_INNER, DT_RANK, 96, dt_b + (size_t)i * D_INNER);
        scan_k<<<16, 256, 0, stream>>>(
            u, dt, dbl, A_log + (size_t)i * D_INNER * D_STATE, Dp + (size_t)i * D_INNER, y);
        gate_k<<<(NTOK * D_INNER) / 256, 256, 0, stream>>>(xz, y);
        gemm_k<2><<<dim3(16, 32), 256, 0, stream>>>(
            y, out_proj + (size_t)i * D_INNER * D_MODEL, x,
            NTOK, D_MODEL, D_INNER, D_INNER, x);
    }

    rmsnorm_k<<<NTOK, 256, 0, stream>>>(x, fin_w, xn);
    gemm_k<0><<<dim3(500, 32), 256, 0, stream>>>(
        xn, head_w, out, NTOK, VOCAB, D_MODEL, D_MODEL, nullptr);
}